// Round 4
// baseline (105.325 us; speedup 1.0000x reference)
//
#include <hip/hip_runtime.h>
#include <math.h>

// Problem constants (from reference): D = 768 -> 192 float4 chunks -> 3 per lane.
#define DIM 768
#define CHUNKS 3          // float4 chunks per lane: 192 / 64
#define WAVES_PER_BLOCK 4 // 256 threads

// Native clang vector type: __builtin_nontemporal_store requires a pointer to
// scalar/native-vector, not HIP's HIP_vector_type<float,4> class.
typedef float v4f __attribute__((ext_vector_type(4)));

// ROUND 4 = MEASUREMENT ROUND. Kernel body is byte-identical to round 3; the
// only change is kernel_launch fires it TWICE (idempotent, deterministic, so
// graph-legal and correctness-preserving). dur_us(round4) - dur_us(round3)
// directly measures one kernel execution, which the top-5 rocprof display
// hides behind the harness's 42 us poison fills. This decides between
// "kernel already at ~13 us memory floor" (declare roofline, revert to 1x)
// and "kernel ~31 us, 2.5x above floor" (optimize).
__global__ __launch_bounds__(256) void word_pool_kernel(
    const float* __restrict__ emb,     // [n_subwords, DIM]
    const int*   __restrict__ offsets, // [n_words, 2]
    const float* __restrict__ attn_w,  // [DIM]
    const float* __restrict__ attn_b,  // [1]
    float*       __restrict__ out,     // [n_words, DIM]
    int n_words)
{
    int wave = (int)((blockIdx.x * blockDim.x + threadIdx.x) >> 6);
    const int lane = (int)(threadIdx.x & 63);
    if (wave >= n_words) return;
    // wave is uniform across the 64 lanes; make that explicit so the compiler
    // emits scalar loads for offsets and a scalar output base address.
    wave = __builtin_amdgcn_readfirstlane(wave);

    const int s0 = offsets[2 * wave + 0];
    const int s1 = offsets[2 * wave + 1];

    // Per-lane fragment of attn_w: v4f chunks {lane, lane+64, lane+128}.
    // Broadcast across all waves -> L2-resident after first touch.
    const v4f* wq = (const v4f*)attn_w;
    v4f wv[CHUNKS];
#pragma unroll
    for (int j = 0; j < CHUNKS; ++j)
        wv[j] = wq[lane + 64 * j];

    v4f* oq = (v4f*)(out + (size_t)wave * DIM);

    if (s1 - s0 == 2) {
        // ---- fast path: exactly two subwords ----
        const v4f* r0p = (const v4f*)(emb + (size_t)s0 * DIM);
        const v4f* r1p = r0p + (DIM / 4);
        v4f r0[CHUNKS], r1[CHUNKS];
        // Issue all 6 loads before any use -> one memory round trip.
#pragma unroll
        for (int j = 0; j < CHUNKS; ++j) r0[j] = r0p[lane + 64 * j];
#pragma unroll
        for (int j = 0; j < CHUNKS; ++j) r1[j] = r1p[lane + 64 * j];

        float d0 = 0.0f, d1 = 0.0f;
#pragma unroll
        for (int j = 0; j < CHUNKS; ++j) {
            d0 += r0[j].x * wv[j].x + r0[j].y * wv[j].y
                + r0[j].z * wv[j].z + r0[j].w * wv[j].w;
            d1 += r1[j].x * wv[j].x + r1[j].y * wv[j].y
                + r1[j].z * wv[j].z + r1[j].w * wv[j].w;
        }
        // Two independent butterfly chains, interleaved for ILP.
#pragma unroll
        for (int off = 32; off > 0; off >>= 1) {
            d0 += __shfl_xor(d0, off, 64);
            d1 += __shfl_xor(d1, off, 64);
        }
        // softmax([d0,d1]) -- bias cancels. Stable sigmoid of diff.
        const float diff = d1 - d0;
        const float t    = expf(-fabsf(diff));
        const float inv  = 1.0f / (1.0f + t);
        const float p1   = (diff >= 0.0f) ? inv : t * inv;
        const float p0   = 1.0f - p1;
#pragma unroll
        for (int j = 0; j < CHUNKS; ++j) {
            v4f v;
            v.x = p0 * r0[j].x + p1 * r1[j].x;
            v.y = p0 * r0[j].y + p1 * r1[j].y;
            v.z = p0 * r0[j].z + p1 * r1[j].z;
            v.w = p0 * r0[j].w + p1 * r1[j].w;
            __builtin_nontemporal_store(v, &oq[lane + 64 * j]);
        }
        return;
    }

    // ---- generic path: online softmax over an arbitrary span ----
    const float bias = attn_b[0];
    float m = -INFINITY;
    float denom = 0.0f;
    v4f acc[CHUNKS];
#pragma unroll
    for (int j = 0; j < CHUNKS; ++j)
        acc[j] = (v4f){0.0f, 0.0f, 0.0f, 0.0f};

    for (int s = s0; s < s1; ++s) {
        const v4f* row = (const v4f*)(emb + (size_t)s * DIM);
        v4f rv[CHUNKS];
        float partial = 0.0f;
#pragma unroll
        for (int j = 0; j < CHUNKS; ++j) {
            rv[j] = row[lane + 64 * j];
            partial += rv[j].x * wv[j].x + rv[j].y * wv[j].y
                     + rv[j].z * wv[j].z + rv[j].w * wv[j].w;
        }
#pragma unroll
        for (int off = 32; off > 0; off >>= 1)
            partial += __shfl_xor(partial, off, 64);
        const float score = partial + bias;

        const float m_new = fmaxf(m, score);
        const float alpha = expf(m - m_new);
        const float p     = expf(score - m_new);
#pragma unroll
        for (int j = 0; j < CHUNKS; ++j) {
            acc[j] = acc[j] * alpha + rv[j] * p;
        }
        denom = denom * alpha + p;
        m = m_new;
    }

    const float inv = 1.0f / denom;
#pragma unroll
    for (int j = 0; j < CHUNKS; ++j) {
        v4f v = acc[j] * inv;
        __builtin_nontemporal_store(v, &oq[lane + 64 * j]);
    }
}

extern "C" void kernel_launch(void* const* d_in, const int* in_sizes, int n_in,
                              void* d_out, int out_size, void* d_ws, size_t ws_size,
                              hipStream_t stream) {
    const float* emb     = (const float*)d_in[0];
    const int*   offsets = (const int*)d_in[1];
    const float* attn_w  = (const float*)d_in[2];
    const float* attn_b  = (const float*)d_in[3];
    float*       out     = (float*)d_out;

    const int n_words = in_sizes[1] / 2;  // [n_words, 2]
    const int blocks  = (n_words + WAVES_PER_BLOCK - 1) / WAVES_PER_BLOCK;

    // Launched TWICE on purpose (measurement round): the kernel is idempotent,
    // so the second launch recomputes the identical output. The dur_us delta
    // vs round 3 gives the kernel's own execution time, which rocprof's top-5
    // display hides behind the harness's poison fills.
    word_pool_kernel<<<blocks, 256, 0, stream>>>(emb, offsets, attn_w, attn_b,
                                                 out, n_words);
    word_pool_kernel<<<blocks, 256, 0, stream>>>(emb, offsets, attn_w, attn_b,
                                                 out, n_words);
}

// Round 5
// 92.041 us; speedup vs baseline: 1.1443x; 1.1443x over previous
//
#include <hip/hip_runtime.h>
#include <math.h>

// Problem constants (from reference): D = 768 -> 192 float4 chunks -> 3 per lane.
#define DIM 768
#define CHUNKS 3          // float4 chunks per lane: 192 / 64
#define WAVES_PER_BLOCK 4 // 256 threads

// Native clang vector type: __builtin_nontemporal_store requires a pointer to
// scalar/native-vector, not HIP's HIP_vector_type<float,4> class.
typedef float v4f __attribute__((ext_vector_type(4)));

// One wave (64 lanes) per word, fully fused score+softmax+weighted-sum.
// Each embedding row is read exactly once from HBM (spans partition the
// subwords) and each output row written once: 50.3 MB + 64 KB read, 25.2 MB
// write = the information-theoretic minimum traffic for this op.
//
// MEASURED (round-4 double-launch A/B): one kernel execution = 11.1 us for
// 75.6 MB => 6.8 TB/s, i.e. >= the ~6.3 TB/s achievable HBM ceiling (second
// launch slightly L3-warm). Kernel is at the memory roofline; the remaining
// ~83 us of bench dur_us is harness fixed cost (268 MB poison fills at 42 us
// each dominate rocprof's top-5).
__global__ __launch_bounds__(256) void word_pool_kernel(
    const float* __restrict__ emb,     // [n_subwords, DIM]
    const int*   __restrict__ offsets, // [n_words, 2]
    const float* __restrict__ attn_w,  // [DIM]
    const float* __restrict__ attn_b,  // [1]
    float*       __restrict__ out,     // [n_words, DIM]
    int n_words)
{
    int wave = (int)((blockIdx.x * blockDim.x + threadIdx.x) >> 6);
    const int lane = (int)(threadIdx.x & 63);
    if (wave >= n_words) return;
    // wave is uniform across the 64 lanes; make that explicit so the compiler
    // emits scalar loads for offsets and a scalar output base address.
    wave = __builtin_amdgcn_readfirstlane(wave);

    const int s0 = offsets[2 * wave + 0];
    const int s1 = offsets[2 * wave + 1];

    // Per-lane fragment of attn_w: v4f chunks {lane, lane+64, lane+128}.
    // Broadcast across all waves -> L2-resident after first touch.
    const v4f* wq = (const v4f*)attn_w;
    v4f wv[CHUNKS];
#pragma unroll
    for (int j = 0; j < CHUNKS; ++j)
        wv[j] = wq[lane + 64 * j];

    v4f* oq = (v4f*)(out + (size_t)wave * DIM);

    if (s1 - s0 == 2) {
        // ---- fast path: exactly two subwords ----
        const v4f* r0p = (const v4f*)(emb + (size_t)s0 * DIM);
        const v4f* r1p = r0p + (DIM / 4);
        v4f r0[CHUNKS], r1[CHUNKS];
        // Issue all 6 loads before any use -> one memory round trip.
#pragma unroll
        for (int j = 0; j < CHUNKS; ++j) r0[j] = r0p[lane + 64 * j];
#pragma unroll
        for (int j = 0; j < CHUNKS; ++j) r1[j] = r1p[lane + 64 * j];

        float d0 = 0.0f, d1 = 0.0f;
#pragma unroll
        for (int j = 0; j < CHUNKS; ++j) {
            d0 += r0[j].x * wv[j].x + r0[j].y * wv[j].y
                + r0[j].z * wv[j].z + r0[j].w * wv[j].w;
            d1 += r1[j].x * wv[j].x + r1[j].y * wv[j].y
                + r1[j].z * wv[j].z + r1[j].w * wv[j].w;
        }
        // Two independent butterfly chains, interleaved for ILP.
#pragma unroll
        for (int off = 32; off > 0; off >>= 1) {
            d0 += __shfl_xor(d0, off, 64);
            d1 += __shfl_xor(d1, off, 64);
        }
        // softmax([d0,d1]) -- bias cancels. Stable sigmoid of diff.
        const float diff = d1 - d0;
        const float t    = expf(-fabsf(diff));
        const float inv  = 1.0f / (1.0f + t);
        const float p1   = (diff >= 0.0f) ? inv : t * inv;
        const float p0   = 1.0f - p1;
#pragma unroll
        for (int j = 0; j < CHUNKS; ++j) {
            v4f v;
            v.x = p0 * r0[j].x + p1 * r1[j].x;
            v.y = p0 * r0[j].y + p1 * r1[j].y;
            v.z = p0 * r0[j].z + p1 * r1[j].z;
            v.w = p0 * r0[j].w + p1 * r1[j].w;
            __builtin_nontemporal_store(v, &oq[lane + 64 * j]);
        }
        return;
    }

    // ---- generic path: online softmax over an arbitrary span ----
    const float bias = attn_b[0];
    float m = -INFINITY;
    float denom = 0.0f;
    v4f acc[CHUNKS];
#pragma unroll
    for (int j = 0; j < CHUNKS; ++j)
        acc[j] = (v4f){0.0f, 0.0f, 0.0f, 0.0f};

    for (int s = s0; s < s1; ++s) {
        const v4f* row = (const v4f*)(emb + (size_t)s * DIM);
        v4f rv[CHUNKS];
        float partial = 0.0f;
#pragma unroll
        for (int j = 0; j < CHUNKS; ++j) {
            rv[j] = row[lane + 64 * j];
            partial += rv[j].x * wv[j].x + rv[j].y * wv[j].y
                     + rv[j].z * wv[j].z + rv[j].w * wv[j].w;
        }
#pragma unroll
        for (int off = 32; off > 0; off >>= 1)
            partial += __shfl_xor(partial, off, 64);
        const float score = partial + bias;

        const float m_new = fmaxf(m, score);
        const float alpha = expf(m - m_new);
        const float p     = expf(score - m_new);
#pragma unroll
        for (int j = 0; j < CHUNKS; ++j) {
            acc[j] = acc[j] * alpha + rv[j] * p;
        }
        denom = denom * alpha + p;
        m = m_new;
    }

    const float inv = 1.0f / denom;
#pragma unroll
    for (int j = 0; j < CHUNKS; ++j) {
        v4f v = acc[j] * inv;
        __builtin_nontemporal_store(v, &oq[lane + 64 * j]);
    }
}

extern "C" void kernel_launch(void* const* d_in, const int* in_sizes, int n_in,
                              void* d_out, int out_size, void* d_ws, size_t ws_size,
                              hipStream_t stream) {
    const float* emb     = (const float*)d_in[0];
    const int*   offsets = (const int*)d_in[1];
    const float* attn_w  = (const float*)d_in[2];
    const float* attn_b  = (const float*)d_in[3];
    float*       out     = (float*)d_out;

    const int n_words = in_sizes[1] / 2;  // [n_words, 2]
    const int blocks  = (n_words + WAVES_PER_BLOCK - 1) / WAVES_PER_BLOCK;

    word_pool_kernel<<<blocks, 256, 0, stream>>>(emb, offsets, attn_w, attn_b,
                                                 out, n_words);
}